// Round 8
// baseline (229.469 us; speedup 1.0000x reference)
//
#include <hip/hip_runtime.h>
#include <math.h>
#include <stdint.h>

// ---------------------------------------------------------------------------
// TransformerLayer (Swin-style) on MI355X. FP32 I/O; bf16 MFMA internals.
// B=2, H=W=128, C=128, NS=8 -> 64 windows x 256 tokens; HID=1024.
// R8: FFN kernels rebuilt with PADDED LDS (stride 68 u16 -> 2-way bank = free)
//     via VGPR staging (padding incompatible with global_load_lds, m104),
//     BK=64 -> 34/27 KB LDS -> 4 blocks/CU. R7 evidence: 6.29M bank-conflict
//     cycles (~10us) from 32-row b128 frag reads at 64B row stride, plus 50%
//     idle at 2 waves/SIMD. prep transposes via LDS tiles (kills 16x sector
//     read amplification).
// ---------------------------------------------------------------------------

typedef unsigned short u16;
typedef __attribute__((ext_vector_type(8))) short bf16x8;   // 8 bf16 (4 VGPRs)
typedef __attribute__((ext_vector_type(4))) short s16x4;    // 8 B, align 8
typedef __attribute__((ext_vector_type(4))) float f32x4;
typedef __attribute__((ext_vector_type(16))) float f32x16;  // 32x32 accumulator
typedef __attribute__((ext_vector_type(4))) short u16x4;

__device__ __forceinline__ u16 f2b(float f) {
    unsigned int i = __float_as_uint(f);
    unsigned int r = (i + 0x7fffu + ((i >> 16) & 1u)) >> 16;
    return (u16)r;
}

// gelu via A-S 7.1.28 erf (|eps|<=5e-4): ONE transcendental (rcp).
__device__ __forceinline__ float gelu_e(float x) {
    float y = fabsf(x) * 0.70710678118f;
    float u = fmaf(y, fmaf(y, fmaf(y, fmaf(y, 0.078108f, 0.000972f),
                                   0.230389f), 0.278393f), 1.0f);
    u = u * u; u = u * u;
    float r = __builtin_amdgcn_rcpf(u);
    return fmaxf(x, 0.f) - 0.5f * fabsf(x) * r;
}

// 16B async global->LDS (m97-verified). LDS dest wave-uniform base + lane*16.
__device__ __forceinline__ void cp16(const void* g, void* l) {
    auto* gp = reinterpret_cast<const __attribute__((address_space(1))) unsigned int*>(
        reinterpret_cast<uintptr_t>(g));
    auto* lp = reinterpret_cast<__attribute__((address_space(3))) unsigned int*>(
        reinterpret_cast<uintptr_t>(l));
    __builtin_amdgcn_global_load_lds(gp, lp, 16, 0, 0);
}

// 8B-granular LDS store/load of a bf16x8 (padded strides break 16B align)
__device__ __forceinline__ void st_lds8(u16* p, bf16x8 v) {
    s16x4 lo, hi;
    lo[0] = v[0]; lo[1] = v[1]; lo[2] = v[2]; lo[3] = v[3];
    hi[0] = v[4]; hi[1] = v[5]; hi[2] = v[6]; hi[3] = v[7];
    *(s16x4*)p = lo;
    *(s16x4*)(p + 4) = hi;
}
__device__ __forceinline__ bf16x8 ld_lds8(const u16* p) {
    s16x4 lo = *(const s16x4*)p;
    s16x4 hi = *(const s16x4*)(p + 4);
    bf16x8 r;
    r[0] = lo[0]; r[1] = lo[1]; r[2] = lo[2]; r[3] = lo[3];
    r[4] = hi[0]; r[5] = hi[1]; r[6] = hi[2]; r[7] = hi[3];
    return r;
}

// window row (b*16384 + win*256 + t) -> source-order row (b*16384 + h*128 + w)
__device__ __forceinline__ int win_map(int gm) {
    int b = gm >> 14, rr = gm & 16383;
    int win = rr >> 8, t = rr & 255;
    int wi = win >> 3, wj = win & 7, i = t >> 4, j = t & 15;
    int h = (wi * 16 + i + 8) & 127;
    int w = (wj * 16 + j + 8) & 127;
    return (b << 14) + h * 128 + w;
}

// ---------------------------------------------------------------------------
// Fused QKV: grid (256, 3). y=0: q=src@Wq, y=1: k=tgt@Wk (window layouts),
// y=2: v=tgt@Wv stored transposed per window. K=128 fully LDS-resident.
// (unchanged from R7 — works)
// ---------------------------------------------------------------------------
__global__ __launch_bounds__(256, 2)
void gemm_qkv(const u16* __restrict__ srcb, const u16* __restrict__ tgtb,
              const u16* __restrict__ Bt, u16* __restrict__ qw,
              u16* __restrict__ kw, u16* __restrict__ vwt)
{
    __shared__ __align__(16) u16 SMEM[32768];   // As[4][128][32] | Bs[4][128][32]
    u16* As = SMEM;
    u16* Bs = SMEM + 16384;
    u16* Ts = SMEM;                              // 128x136 epilogue overlay

    const int tid = threadIdx.x;
    const int w = tid >> 6, lane = tid & 63;
    const int lm = lane & 15, q = lane >> 4;
    const int wm = w >> 1, wn = w & 1;
    const int m0 = blockIdx.x * 128;
    const int y = blockIdx.y;
    const u16* Ab = (y == 0) ? srcb : tgtb;

#pragma unroll
    for (int s = 0; s < 4; ++s)
#pragma unroll
        for (int i = 0; i < 2; ++i) {
            int row = w * 32 + i * 16 + (lane >> 2);
            int kc = s * 32 + (lane & 3) * 8;
            cp16(Ab + (size_t)win_map(m0 + row) * 128 + kc,
                 (void*)(As + (s * 128 + w * 32 + i * 16) * 32));
            cp16(Bt + (size_t)(y * 128 + row) * 128 + kc,
                 (void*)(Bs + (s * 128 + w * 32 + i * 16) * 32));
        }
    __syncthreads();

    f32x4 acc[4][4] = {};
#pragma unroll
    for (int s = 0; s < 4; ++s) {
        bf16x8 af[4], bfr[4];
#pragma unroll
        for (int t = 0; t < 4; ++t)
            af[t] = *(const bf16x8*)(As + (s * 128 + wm * 64 + t * 16 + lm) * 32 + q * 8);
#pragma unroll
        for (int t = 0; t < 4; ++t)
            bfr[t] = *(const bf16x8*)(Bs + (s * 128 + wn * 64 + t * 16 + lm) * 32 + q * 8);
#pragma unroll
        for (int mt = 0; mt < 4; ++mt)
#pragma unroll
            for (int nt = 0; nt < 4; ++nt)
                acc[mt][nt] = __builtin_amdgcn_mfma_f32_16x16x32_bf16(
                    af[mt], bfr[nt], acc[mt][nt], 0, 0, 0);
    }

    __syncthreads();
#pragma unroll
    for (int mt = 0; mt < 4; ++mt)
#pragma unroll
        for (int nt = 0; nt < 4; ++nt)
#pragma unroll
            for (int r = 0; r < 4; ++r) {
                int rowl = wm * 64 + mt * 16 + q * 4 + r;
                int col = wn * 64 + nt * 16 + lm;
                int idx = (y == 2) ? col * 136 + rowl : rowl * 136 + col;
                Ts[idx] = f2b(acc[mt][nt][r]);
            }
    __syncthreads();
    const int c8 = (tid & 15) * 8;
#pragma unroll
    for (int i = 0; i < 8; ++i) {
        int rr = i * 16 + (tid >> 4);
        bf16x8 t = *(const bf16x8*)(Ts + rr * 136 + c8);
        if (y == 2) {
            int wix = m0 >> 8, tok0 = m0 & 255;   // vwT[(b*64+win)*128+ch][tok]
            *(bf16x8*)(vwt + (size_t)wix * 32768 + (size_t)rr * 256 + tok0 + c8) = t;
        } else {
            u16* Cv = (y == 0) ? qw : kw;
            *(bf16x8*)(Cv + (size_t)(m0 + rr) * 128 + c8) = t;
        }
    }
}

// ---------------------------------------------------------------------------
// FFN1: gelu(cat(src,msg) @ W1) -> bf16 HID. 32x32x16 MFMA, BM=BN=128, BK=64.
// Padded LDS stride 68 u16 (136 B -> bank step 2 -> 2-way = free) via VGPR
// staging. 34 KB LDS -> 4 blocks/CU. Direct full-sector bf16 stores.
// ---------------------------------------------------------------------------
__global__ __launch_bounds__(256, 4)
void gemm_ffn1(const u16* __restrict__ A0, const u16* __restrict__ A1,
               const u16* __restrict__ Bt, u16* __restrict__ C)
{
    __shared__ __align__(16) u16 As[128 * 68];   // 17408 B
    __shared__ __align__(16) u16 Bs[128 * 68];   // 17408 B

    const int tid = threadIdx.x;
    const int lane = tid & 63, w = tid >> 6;
    const int l32 = lane & 31, lh = lane >> 5;
    const int wm = w >> 1, wn = w & 1;
    const int m0 = blockIdx.x * 128, n0 = blockIdx.y * 128;

    f32x16 acc[2][2] = {};
#pragma unroll
    for (int kt = 0; kt < 4; ++kt) {             // K=256, BK=64
        const u16* Ab = (kt < 2) ? A0 : A1;      // cat(src, msg)
        const int ka = (kt & 1) * 64;
        __syncthreads();
#pragma unroll
        for (int i = 0; i < 4; ++i) {            // A: 128 rows x 64, ldg 128
            int id = i * 256 + tid, row = id >> 3, c = id & 7;
            bf16x8 v = *(const bf16x8*)(Ab + (size_t)(m0 + row) * 128 + ka + c * 8);
            st_lds8(As + row * 68 + c * 8, v);
        }
#pragma unroll
        for (int i = 0; i < 4; ++i) {            // B: 128 rows x 64, ldg 256
            int id = i * 256 + tid, row = id >> 3, c = id & 7;
            bf16x8 v = *(const bf16x8*)(Bt + (size_t)(n0 + row) * 256 + kt * 64 + c * 8);
            st_lds8(Bs + row * 68 + c * 8, v);
        }
        __syncthreads();
#pragma unroll
        for (int kc = 0; kc < 4; ++kc) {
            bf16x8 af[2], bfr[2];
#pragma unroll
            for (int mt = 0; mt < 2; ++mt)
                af[mt] = ld_lds8(As + (wm * 64 + mt * 32 + l32) * 68 + kc * 16 + lh * 8);
#pragma unroll
            for (int nt = 0; nt < 2; ++nt)
                bfr[nt] = ld_lds8(Bs + (wn * 64 + nt * 32 + l32) * 68 + kc * 16 + lh * 8);
#pragma unroll
            for (int mt = 0; mt < 2; ++mt)
#pragma unroll
                for (int nt = 0; nt < 2; ++nt)
                    acc[mt][nt] = __builtin_amdgcn_mfma_f32_32x32x16_bf16(
                        af[mt], bfr[nt], acc[mt][nt], 0, 0, 0);
        }
    }

    // C/D 32x32 layout: col=lane&31, row=(r&3)+8*(r>>2)+4*lh (verified R6/R7)
#pragma unroll
    for (int mt = 0; mt < 2; ++mt)
#pragma unroll
        for (int nt = 0; nt < 2; ++nt) {
            int col = n0 + wn * 64 + nt * 32 + l32;
            int rbase = m0 + wm * 64 + mt * 32 + 4 * lh;
#pragma unroll
            for (int r = 0; r < 16; ++r) {
                int row = rbase + (r & 3) + 8 * (r >> 2);
                C[(size_t)row * 1024 + col] = f2b(gelu_e(acc[mt][nt][r]));
            }
        }
}

// ---------------------------------------------------------------------------
// FFN2 + LN + residual. 32x32x16 MFMA, BM=64, BN=128, BK=64 streaming over
// K=1024. Padded LDS; 27 KB -> 4+ blocks/CU. LN stats per 32-lane half +
// 1 KB LDS exchange across the wn wave pair. fp32 full-sector stores.
// ---------------------------------------------------------------------------
__global__ __launch_bounds__(256, 4)
void gemm_ffn2(const u16* __restrict__ A, const u16* __restrict__ Bt,
               const float* __restrict__ g, const float* __restrict__ bb,
               const float* __restrict__ resid, float* __restrict__ outv)
{
    __shared__ __align__(16) u16 As[64 * 68];    // 8704 B
    __shared__ __align__(16) u16 Bs[128 * 68];   // 17408 B
    __shared__ float stats[64][2][2];            // [row][wn][s,s2]  1 KB

    const int tid = threadIdx.x;
    const int lane = tid & 63, w = tid >> 6;
    const int l32 = lane & 31, lh = lane >> 5;
    const int wm = w >> 1, wn = w & 1;
    const int m0 = blockIdx.x * 64;

    f32x16 acc[2] = {};
#pragma unroll
    for (int kt = 0; kt < 16; ++kt) {            // K=1024, BK=64
        __syncthreads();
#pragma unroll
        for (int i = 0; i < 2; ++i) {            // A: 64 rows x 64, ldg 1024
            int id = i * 256 + tid, row = id >> 3, c = id & 7;
            bf16x8 v = *(const bf16x8*)(A + (size_t)(m0 + row) * 1024 + kt * 64 + c * 8);
            st_lds8(As + row * 68 + c * 8, v);
        }
#pragma unroll
        for (int i = 0; i < 4; ++i) {            // B: 128 rows x 64, ldg 1024
            int id = i * 256 + tid, row = id >> 3, c = id & 7;
            bf16x8 v = *(const bf16x8*)(Bt + (size_t)row * 1024 + kt * 64 + c * 8);
            st_lds8(Bs + row * 68 + c * 8, v);
        }
        __syncthreads();
#pragma unroll
        for (int kc = 0; kc < 4; ++kc) {
            bf16x8 af = ld_lds8(As + (wm * 32 + l32) * 68 + kc * 16 + lh * 8);
            bf16x8 bf0 = ld_lds8(Bs + (wn * 64 + l32) * 68 + kc * 16 + lh * 8);
            bf16x8 bf1 = ld_lds8(Bs + (wn * 64 + 32 + l32) * 68 + kc * 16 + lh * 8);
            acc[0] = __builtin_amdgcn_mfma_f32_32x32x16_bf16(af, bf0, acc[0], 0, 0, 0);
            acc[1] = __builtin_amdgcn_mfma_f32_32x32x16_bf16(af, bf1, acc[1], 0, 0, 0);
        }
    }

    // LN stats: for fixed r, all 32 lanes of a half hold the SAME row
    // (row = wm*32 + (r&3)+8*(r>>2)+4*lh, independent of l32).
#pragma unroll
    for (int r = 0; r < 16; ++r) {
        float v0 = acc[0][r], v1 = acc[1][r];
        float s1 = v0 + v1, s2 = v0 * v0 + v1 * v1;
        s1 += __shfl_xor(s1, 1);  s2 += __shfl_xor(s2, 1);
        s1 += __shfl_xor(s1, 2);  s2 += __shfl_xor(s2, 2);
        s1 += __shfl_xor(s1, 4);  s2 += __shfl_xor(s2, 4);
        s1 += __shfl_xor(s1, 8);  s2 += __shfl_xor(s2, 8);
        s1 += __shfl_xor(s1, 16); s2 += __shfl_xor(s2, 16);
        if (l32 == 0) {
            int row = wm * 32 + (r & 3) + 8 * (r >> 2) + 4 * lh;
            stats[row][wn][0] = s1;
            stats[row][wn][1] = s2;
        }
    }
    __syncthreads();

    float gv[2], bv[2];
#pragma unroll
    for (int nt = 0; nt < 2; ++nt) {
        int col = wn * 64 + nt * 32 + l32;
        gv[nt] = g[col]; bv[nt] = bb[col];
    }
#pragma unroll
    for (int r = 0; r < 16; ++r) {
        int row = wm * 32 + (r & 3) + 8 * (r >> 2) + 4 * lh;
        float s1 = stats[row][0][0] + stats[row][1][0];
        float s2 = stats[row][0][1] + stats[row][1][1];
        float mean = s1 * (1.f / 128.f);
        float var = fmaxf(s2 * (1.f / 128.f) - mean * mean, 0.f);
        float rs = rsqrtf(var + 1e-5f);
#pragma unroll
        for (int nt = 0; nt < 2; ++nt) {
            int col = wn * 64 + nt * 32 + l32;
            size_t gi = (size_t)(m0 + row) * 128 + col;
            outv[gi] = (acc[nt][r] - mean) * rs * gv[nt] + bv[nt] + resid[gi];
        }
    }
}

// ---------------------------------------------------------------------------
// Fused attention + msg-proj + LayerNorm (unchanged from R7 — works).
// ---------------------------------------------------------------------------
__global__ __launch_bounds__(256, 2)
void attn_msg(const u16* __restrict__ qw, const u16* __restrict__ kw,
              const u16* __restrict__ vt, const u16* __restrict__ wmt,
              const float* __restrict__ g, const float* __restrict__ bb,
              u16* __restrict__ msgb)
{
    __shared__ __align__(16) u16 Ps[64 * 264];   // P (stride 264); Q/Ot overlays
    __shared__ __align__(16) u16 B32[16384];     // 32KB staging buffer

    const int tid = threadIdx.x, w = tid >> 6, lane = tid & 63;
    const int lm = lane & 15, q = lane >> 4;
    const int l4r = lane >> 2, l4c = (lane & 3) * 8;
    const int bid = blockIdx.x;
    const int qc = bid & 3, win = (bid >> 2) & 63, b = bid >> 8;
    const int wi = win >> 3, wj = win & 7;
    const int q0 = qc * 64;
    const size_t wbase = (size_t)(b * 64 + win);
    const u16* kwb = kw + wbase * 256 * 128;
    const u16* qwb = qw + wbase * 256 * 128;
    const u16* vtb = vt + wbase * 128 * 256;

    u16* Qs = Ps;
#pragma unroll
    for (int i = 0; i < 4; ++i)
        cp16(qwb + (size_t)(q0 + w * 16 + l4r) * 128 + i * 32 + l4c,
             (void*)(Qs + (i * 64 + w * 16) * 32));
#pragma unroll
    for (int s = 0; s < 4; ++s)
#pragma unroll
        for (int i = 0; i < 2; ++i) {
            int tok = w * 32 + i * 16 + l4r;
            cp16(kwb + (size_t)tok * 128 + s * 32 + l4c,
                 (void*)(B32 + (s * 128 + w * 32 + i * 16) * 32));
        }
    __syncthreads();

    bf16x8 af[4];
#pragma unroll
    for (int kt = 0; kt < 4; ++kt)
        af[kt] = *(const bf16x8*)(Qs + (kt * 64 + w * 16 + lm) * 32 + q * 8);

    f32x4 s[16];
#pragma unroll
    for (int nt = 0; nt < 16; ++nt) { f32x4 z = {0.f, 0.f, 0.f, 0.f}; s[nt] = z; }
#pragma unroll
    for (int kt = 0; kt < 4; ++kt)
#pragma unroll
        for (int nt = 0; nt < 8; ++nt) {
            bf16x8 bf = *(const bf16x8*)(B32 + (kt * 128 + nt * 16 + lm) * 32 + q * 8);
            s[nt] = __builtin_amdgcn_mfma_f32_16x16x32_bf16(af[kt], bf, s[nt], 0, 0, 0);
        }
    __syncthreads();
#pragma unroll
    for (int ss = 0; ss < 4; ++ss)
#pragma unroll
        for (int i = 0; i < 2; ++i) {
            int tok = 128 + w * 32 + i * 16 + l4r;
            cp16(kwb + (size_t)tok * 128 + ss * 32 + l4c,
                 (void*)(B32 + (ss * 128 + w * 32 + i * 16) * 32));
        }
    __syncthreads();
#pragma unroll
    for (int kt = 0; kt < 4; ++kt)
#pragma unroll
        for (int nt = 8; nt < 16; ++nt) {
            bf16x8 bf = *(const bf16x8*)(B32 + (kt * 128 + (nt - 8) * 16 + lm) * 32 + q * 8);
            s[nt] = __builtin_amdgcn_mfma_f32_16x16x32_bf16(af[kt], bf, s[nt], 0, 0, 0);
        }
    __syncthreads();

#pragma unroll
    for (int tt = 0; tt < 4; ++tt)
#pragma unroll
        for (int i = 0; i < 2; ++i) {
            int ch = w * 32 + i * 16 + l4r;
            cp16(vtb + (size_t)ch * 256 + tt * 32 + l4c,
                 (void*)(B32 + (tt * 128 + w * 32 + i * 16) * 32));
        }

    int idk[16];
#pragma unroll
    for (int nt = 0; nt < 16; ++nt) {
        int rh = (wi == 7) ? ((nt >= 8) ? 2 : 1) : 0;
        int rw = (wj == 7) ? ((lm >= 8) ? 2 : 1) : 0;
        idk[nt] = rh * 3 + rw;
    }
    const float scale = 0.08838834764831845f;
#pragma unroll
    for (int r = 0; r < 4; ++r) {
        int tq = q0 + w * 16 + q * 4 + r;
        int iq = tq >> 4, jq = tq & 15;
        int rhq = (wi == 7) ? ((iq >= 8) ? 2 : 1) : 0;
        int rwq = (wj == 7) ? ((jq >= 8) ? 2 : 1) : 0;
        int idq = rhq * 3 + rwq;
        float sv[16];
        float mx = -1e30f;
#pragma unroll
        for (int nt = 0; nt < 16; ++nt) {
            float x = s[nt][r] * scale + ((idq != idk[nt]) ? -100.f : 0.f);
            sv[nt] = x; mx = fmaxf(mx, x);
        }
        mx = fmaxf(mx, __shfl_xor(mx, 1));
        mx = fmaxf(mx, __shfl_xor(mx, 2));
        mx = fmaxf(mx, __shfl_xor(mx, 4));
        mx = fmaxf(mx, __shfl_xor(mx, 8));
        float sum = 0.f;
#pragma unroll
        for (int nt = 0; nt < 16; ++nt) { float e = __expf(sv[nt] - mx); sv[nt] = e; sum += e; }
        sum += __shfl_xor(sum, 1);
        sum += __shfl_xor(sum, 2);
        sum += __shfl_xor(sum, 4);
        sum += __shfl_xor(sum, 8);
        float inv = 1.0f / sum;
#pragma unroll
        for (int nt = 0; nt < 16; ++nt)
            Ps[(w * 16 + q * 4 + r) * 264 + nt * 16 + lm] = f2b(sv[nt] * inv);
    }
    __syncthreads();

    f32x4 o[8];
#pragma unroll
    for (int nt = 0; nt < 8; ++nt) { f32x4 z = {0.f, 0.f, 0.f, 0.f}; o[nt] = z; }
#pragma unroll
    for (int tt = 0; tt < 4; ++tt) {
        bf16x8 pf = *(const bf16x8*)(Ps + (w * 16 + lm) * 264 + tt * 32 + q * 8);
#pragma unroll
        for (int nt = 0; nt < 8; ++nt) {
            bf16x8 vf = *(const bf16x8*)(B32 + (tt * 128 + nt * 16 + lm) * 32 + q * 8);
            o[nt] = __builtin_amdgcn_mfma_f32_16x16x32_bf16(pf, vf, o[nt], 0, 0, 0);
        }
    }
    __syncthreads();
#pragma unroll
    for (int tt = 0; tt < 4; ++tt)
#pragma unroll
        for (int i = 0; i < 2; ++i) {
            int ch = w * 32 + i * 16 + l4r;
            cp16(vtb + (size_t)ch * 256 + 128 + tt * 32 + l4c,
                 (void*)(B32 + (tt * 128 + w * 32 + i * 16) * 32));
        }
    __syncthreads();
#pragma unroll
    for (int tt = 4; tt < 8; ++tt) {
        bf16x8 pf = *(const bf16x8*)(Ps + (w * 16 + lm) * 264 + tt * 32 + q * 8);
#pragma unroll
        for (int nt = 0; nt < 8; ++nt) {
            bf16x8 vf = *(const bf16x8*)(B32 + ((tt - 4) * 128 + nt * 16 + lm) * 32 + q * 8);
            o[nt] = __builtin_amdgcn_mfma_f32_16x16x32_bf16(pf, vf, o[nt], 0, 0, 0);
        }
    }
    __syncthreads();

#pragma unroll
    for (int ss = 0; ss < 4; ++ss)
#pragma unroll
        for (int i = 0; i < 2; ++i) {
            int n = w * 32 + i * 16 + l4r;
            cp16(wmt + (size_t)n * 128 + ss * 32 + l4c,
                 (void*)(B32 + (ss * 128 + w * 32 + i * 16) * 32));
        }
    u16* Ot = Ps;   // [64][136]
#pragma unroll
    for (int r = 0; r < 4; ++r) {
        int rl = w * 16 + q * 4 + r;
#pragma unroll
        for (int nt = 0; nt < 8; ++nt)
            Ot[rl * 136 + nt * 16 + lm] = f2b(o[nt][r]);
    }
    __syncthreads();

    f32x4 macc[8];
#pragma unroll
    for (int n2 = 0; n2 < 8; ++n2) { f32x4 z = {0.f, 0.f, 0.f, 0.f}; macc[n2] = z; }
#pragma unroll
    for (int kt = 0; kt < 4; ++kt) {
        bf16x8 paf = *(const bf16x8*)(Ot + (w * 16 + lm) * 136 + kt * 32 + q * 8);
#pragma unroll
        for (int n2 = 0; n2 < 8; ++n2) {
            bf16x8 wf = *(const bf16x8*)(B32 + (kt * 128 + n2 * 16 + lm) * 32 + q * 8);
            macc[n2] = __builtin_amdgcn_mfma_f32_16x16x32_bf16(paf, wf, macc[n2], 0, 0, 0);
        }
    }

    float gv[8], bv[8];
#pragma unroll
    for (int n2 = 0; n2 < 8; ++n2) {
        int col = n2 * 16 + lm;
        gv[n2] = g[col]; bv[n2] = bb[col];
    }
#pragma unroll
    for (int r = 0; r < 4; ++r) {
        float s1 = 0.f, s2 = 0.f;
#pragma unroll
        for (int n2 = 0; n2 < 8; ++n2) {
            float v = macc[n2][r];
            s1 += v; s2 += v * v;
        }
        s1 += __shfl_xor(s1, 1); s2 += __shfl_xor(s2, 1);
        s1 += __shfl_xor(s1, 2); s2 += __shfl_xor(s2, 2);
        s1 += __shfl_xor(s1, 4); s2 += __shfl_xor(s2, 4);
        s1 += __shfl_xor(s1, 8); s2 += __shfl_xor(s2, 8);
        float mean = s1 * (1.f / 128.f);
        float var = fmaxf(s2 * (1.f / 128.f) - mean * mean, 0.f);
        float rs = rsqrtf(var + 1e-5f);
        int t = q0 + w * 16 + q * 4 + r;
        int ii = t >> 4, jj = t & 15;
        int h = (wi * 16 + ii + 8) & 127;
        int w2 = (wj * 16 + jj + 8) & 127;
        size_t orow = ((size_t)b * 16384 + h * 128 + w2) * 128;
#pragma unroll
        for (int n2 = 0; n2 < 8; ++n2)
            msgb[orow + n2 * 16 + lm] = f2b((macc[n2][r] - mean) * rs * gv[n2] + bv[n2]);
    }
}

// ---------------------------------------------------------------------------
// Prep: LDS-tiled weight transposes (64x64 fp32 tiles, both sides coalesced)
// + fp32->bf16 activation cast. Blocks 0..111 = transpose tiles, rest = cast.
// ---------------------------------------------------------------------------
__global__ void prep_all(const float* __restrict__ Wq, const float* __restrict__ Wk,
                         const float* __restrict__ Wv, const float* __restrict__ Wm,
                         const float* __restrict__ W1, const float* __restrict__ W2,
                         const float* __restrict__ src, const float* __restrict__ tgt,
                         u16* __restrict__ ws, u16* __restrict__ srcb,
                         u16* __restrict__ tgtb)
{
    __shared__ float T[64][65];
    int bx = blockIdx.x;
    if (bx < 112) {
        const float* sp; u16* dst; int R, C, r0, c0;
        if (bx < 16) {                 // Wq,Wk,Wv,Wm: (128,128)
            int m = bx >> 2;
            sp = (m == 0) ? Wq : (m == 1) ? Wk : (m == 2) ? Wv : Wm;
            dst = ws + m * 16384; R = 128; C = 128;
            r0 = ((bx >> 1) & 1) * 64; c0 = (bx & 1) * 64;
        } else if (bx < 80) {          // W1: (256,1024) -> dst (1024,256)
            int e = bx - 16;
            sp = W1; dst = ws + 65536; R = 256; C = 1024;
            r0 = (e >> 4) * 64; c0 = (e & 15) * 64;
        } else {                       // W2: (1024,128) -> dst (128,1024)
            int e = bx - 80;
            sp = W2; dst = ws + 327680; R = 1024; C = 128;
            r0 = (e >> 1) * 64; c0 = (e & 1) * 64;
        }
        int tc = threadIdx.x & 63, tg = threadIdx.x >> 6;
#pragma unroll
        for (int i = 0; i < 16; ++i) {
            int r = tg * 16 + i;
            T[r][tc] = sp[(size_t)(r0 + r) * C + c0 + tc];
        }
        __syncthreads();
#pragma unroll
        for (int j = 0; j < 16; ++j) {
            int cc = tg * 16 + j;
            dst[(size_t)(c0 + cc) * R + r0 + tc] = f2b(T[tc][cc]);
        }
    } else {
        int idx = (bx - 112) * 256 + threadIdx.x;   // 0..2097151
        const float* s; u16* d; int i;
        if (idx < 1048576) { s = src; d = srcb; i = idx * 4; }
        else               { s = tgt; d = tgtb; i = (idx - 1048576) * 4; }
        f32x4 v = *(const f32x4*)(s + i);
        u16x4 o; o[0] = f2b(v[0]); o[1] = f2b(v[1]); o[2] = f2b(v[2]); o[3] = f2b(v[3]);
        *(u16x4*)(d + i) = o;
    }
}

// ---------------------------------------------------------------------------
// Workspace layout (u16 element offsets)
// ---------------------------------------------------------------------------
#define OFF_WQT  0u            // concat [WqT;WkT;WvT] 3x(128x128)
#define OFF_WMT  49152u
#define OFF_W1T  65536u
#define OFF_W2T  327680u
#define OFF_SRCB 458752u
#define OFF_TGTB 4653056u
#define OFF_QW   8847360u
#define OFF_KW   13041664u
#define OFF_VWT  17235968u
#define OFF_MSGB 21430272u     // bf16 msg, source-order
#define OFF_HID  25624576u     // bf16 32768x1024, ends 59179008

extern "C" void kernel_launch(void* const* d_in, const int* in_sizes, int n_in,
                              void* d_out, int out_size, void* d_ws, size_t ws_size,
                              hipStream_t stream)
{
    (void)in_sizes; (void)n_in; (void)out_size; (void)ws_size;
    const float* source = (const float*)d_in[0];
    const float* target = (const float*)d_in[1];
    const float* Wq = (const float*)d_in[2];
    const float* Wk = (const float*)d_in[3];
    const float* Wv = (const float*)d_in[4];
    const float* Wm = (const float*)d_in[5];
    const float* g1 = (const float*)d_in[6];
    const float* b1 = (const float*)d_in[7];
    const float* W1 = (const float*)d_in[8];
    const float* W2 = (const float*)d_in[9];
    const float* g2 = (const float*)d_in[10];
    const float* b2 = (const float*)d_in[11];
    u16* ws = (u16*)d_ws;
    float* out = (float*)d_out;

    prep_all<<<112 + 8192, 256, 0, stream>>>(Wq, Wk, Wv, Wm, W1, W2, source, target,
                                             ws, ws + OFF_SRCB, ws + OFF_TGTB);
    gemm_qkv<<<dim3(256, 3), 256, 0, stream>>>(
        ws + OFF_SRCB, ws + OFF_TGTB, ws + OFF_WQT,
        ws + OFF_QW, ws + OFF_KW, ws + OFF_VWT);
    attn_msg<<<512, 256, 0, stream>>>(
        ws + OFF_QW, ws + OFF_KW, ws + OFF_VWT, ws + OFF_WMT, g1, b1,
        ws + OFF_MSGB);
    gemm_ffn1<<<dim3(256, 8), 256, 0, stream>>>(
        ws + OFF_SRCB, ws + OFF_MSGB, ws + OFF_W1T, ws + OFF_HID);
    gemm_ffn2<<<512, 256, 0, stream>>>(
        ws + OFF_HID, ws + OFF_W2T, g2, b2, source, out);
}